// Round 7
// baseline (295.628 us; speedup 1.0000x reference)
//
#include <hip/hip_runtime.h>

#define Bn    256
#define Cc    7
#define Nn    16384
#define HIDW  256
#define SEL   3
#define Mrows (Bn * Cc)            // 1792
#define KSPLIT 16
#define KCHUNK (Nn / KSPLIT)       // 1024
#define BK    32
#define PART_STRIDE ((size_t)Mrows * HIDW)

typedef __attribute__((ext_vector_type(8))) short bf16x8;
typedef __attribute__((ext_vector_type(4))) float floatx4;
typedef __attribute__((ext_vector_type(4))) unsigned int uint32x4;

// pack high-16 bits of two fp32 words: low ushort = ua>>16, high = ub>>16
__device__ __forceinline__ unsigned pack_hi16(unsigned ua, unsigned ub) {
#if __has_builtin(__builtin_amdgcn_perm)
    return __builtin_amdgcn_perm(ub, ua, 0x07060302u);
#else
    return (ua >> 16) | (ub & 0xffff0000u);
#endif
}

// truncation hi/lo split of a pair of floats -> packed hi word + packed lo word
__device__ __forceinline__ void split2(float a, float b, unsigned& hp, unsigned& lp) {
    unsigned ua = __float_as_uint(a), ub = __float_as_uint(b);
    float fa = __uint_as_float(ua & 0xffff0000u);
    float fb = __uint_as_float(ub & 0xffff0000u);
    float la = a - fa, lb = b - fb;            // exact residuals
    hp = pack_hi16(ua, ub);
    lp = pack_hi16(__float_as_uint(la), __float_as_uint(lb));
}

__device__ __forceinline__ bf16x8 mk_bf16x8(unsigned a, unsigned b, unsigned c, unsigned d) {
    uint32x4 u = {a, b, c, d};
    return __builtin_bit_cast(bf16x8, u);
}

// 8 consecutive-k fp32 values (two float4) -> bf16 hi and lo MFMA fragments
__device__ __forceinline__ void split_frag(const float4& x, const float4& y,
                                           bf16x8& hi, bf16x8& lo) {
    unsigned h0, h1, h2, h3, l0, l1, l2, l3;
    split2(x.x, x.y, h0, l0);
    split2(x.z, x.w, h1, l1);
    split2(y.x, y.y, h2, l2);
    split2(y.z, y.w, h3, l3);
    hi = mk_bf16x8(h0, h1, h2, h3);
    lo = mk_bf16x8(l0, l1, l2, l3);
}

// ---------------------------------------------------------------------------
// K0: w1[k][n] fp32 -> fragment-ordered bf16 hi/lo planes (trunc split).
// chunk(c,T,lane) holds B[k=c*32+(lane>>4)*8+j][n=T*16+(lane&15)], j=0..7,
// at ushort offset ((c*16+T)*64+lane)*8.   (unchanged from round-0)
// ---------------------------------------------------------------------------
__global__ __launch_bounds__(256) void convert_w1(const float* __restrict__ w1,
                                                  unsigned short* __restrict__ bhi,
                                                  unsigned short* __restrict__ blo) {
    const int id = blockIdx.x * 256 + threadIdx.x;
    const int l  = id & 63;
    const int ct = id >> 6;
    const int T  = ct & 15;
    const int c  = ct >> 4;
    const int n  = T * 16 + (l & 15);
    const int k  = c * 32 + (l >> 4) * 8;
    float f[8];
#pragma unroll
    for (int j = 0; j < 8; ++j) f[j] = w1[(size_t)(k + j) * HIDW + n];
    unsigned hp[4], lp[4];
#pragma unroll
    for (int m = 0; m < 4; ++m) split2(f[2 * m], f[2 * m + 1], hp[m], lp[m]);
    *(uint4*)(bhi + (size_t)id * 8) = make_uint4(hp[0], hp[1], hp[2], hp[3]);
    *(uint4*)(blo + (size_t)id * 8) = make_uint4(lp[0], lp[1], lp[2], lp[3]);
}

// ---------------------------------------------------------------------------
// K1: MFMA GEMM  part[s][M][256] = feat[M][Kslice] @ w1[Kslice][256]
//   128x128 tile, 4 waves 2x2 (wave tile 64x64), 16x16x32 bf16, 3-pass split.
//   *** NO LDS, NO BARRIERS ***  (round-4 analysis: 96 KB/iter of LDS port
//   traffic ~= 2300 of the 3130 cy/block-iter -- LDS-bandwidth-bound).
//   A: direct global->reg fp32, split in reg. Lane l covers row (l&15),
//      k=(l>>4)*8+0..7 of each 16-row fragment; lanes {l,l+16,l+32,l+48}
//      share a row so the dwordx4 pair fully covers 128 B/row (L1-merged).
//      wn-duplication (2 waves read same A) is L1-absorbed.
//   B: direct global->reg from the fragment-ordered hi/lo planes, perfectly
//      coalesced 1 KB loads; wm-duplication L2-absorbed.
//   Pure dataflow loop: compiler schedules/pipelines freely (no fences).
//   Accumulation order identical to round-4 -> absmax stays 0.
// ---------------------------------------------------------------------------
__global__ __launch_bounds__(256) void gemm_mfma(const float* __restrict__ A,
                                                 const unsigned short* __restrict__ Bhi,
                                                 const unsigned short* __restrict__ Blo,
                                                 float* __restrict__ part) {
    // XCD-pairing swizzle: hardware round-robins blockIdx.x%8 across the 8
    // XCDs. id = (q<<4)|(bx<<3)|r8 -> ys = r8*28+q, so for a fixed XCD r8 the
    // two bx-twins of each (y,s) are adjacent in dispatch order: the A slice
    // is read twice while L2-hot, and each XCD's B working set (2 s-slices,
    // ~2 MB) stays L2-resident.
    const int id  = blockIdx.x;          // 0..447
    const int r8  = id & 7;
    const int bx  = (id >> 3) & 1;
    const int q   = id >> 4;             // 0..27
    const int ys  = r8 * 28 + q;         // 0..223, bijective over (r8,q)
    const int y   = ys % 14;
    const int s   = ys / 14;             // 0..15

    const int m0 = y * 128;
    const int k0 = s * KCHUNK;
    const int t  = threadIdx.x;
    const int lane = t & 63;
    const int w    = t >> 6;
    const int wm   = w & 1;
    const int wn   = w >> 1;

    // A fragment base: row = m0 + wm*64 + i*16 + (lane&15), k = k0 + (lane>>4)*8
    const float* aptr = A + (size_t)(m0 + wm * 64 + (lane & 15)) * Nn
                          + k0 + (lane >> 4) * 8;
    // B fragment base for this wave (frag j at +j*512, chunk step 16*512)
    const unsigned short* bptr_h = Bhi + ((size_t)(k0 >> 5) * 16 + bx * 8 + wn * 4) * 512 + lane * 8;
    const unsigned short* bptr_l = Blo + ((size_t)(k0 >> 5) * 16 + bx * 8 + wn * 4) * 512 + lane * 8;

    floatx4 acc[4][4];
#pragma unroll
    for (int i = 0; i < 4; ++i)
#pragma unroll
        for (int j = 0; j < 4; ++j) acc[i][j] = (floatx4)0.0f;

    // prologue: A(0) fp32 into registers
    float4 a[4][2];
#pragma unroll
    for (int i = 0; i < 4; ++i) {
        a[i][0] = *(const float4*)(aptr + (size_t)i * 16 * Nn);
        a[i][1] = *(const float4*)(aptr + (size_t)i * 16 * Nn + 4);
    }

#pragma unroll 2
    for (int kk = 0; kk < KCHUNK; kk += BK) {
        // B frags for this k-chunk (issued early; L2-hot; covered by split VALU)
        const unsigned short* bh = bptr_h + (size_t)(kk >> 5) * 8192;
        const unsigned short* bl = bptr_l + (size_t)(kk >> 5) * 8192;
        bf16x8 fbh[4], fbl[4];
#pragma unroll
        for (int j = 0; j < 4; ++j) {
            fbh[j] = *(const bf16x8*)(bh + j * 512);
            fbl[j] = *(const bf16x8*)(bl + j * 512);
        }
        // split current A into hi/lo fragments (reg-only VALU)
        bf16x8 ah[4], al[4];
#pragma unroll
        for (int i = 0; i < 4; ++i) split_frag(a[i][0], a[i][1], ah[i], al[i]);
        // prefetch next A (clamped dummy reload on last iter keeps code uniform;
        // the reload is L1-hot and its values are never used)
        const int kn = (kk + BK < KCHUNK) ? (kk + BK) : kk;
#pragma unroll
        for (int i = 0; i < 4; ++i) {
            a[i][0] = *(const float4*)(aptr + (size_t)i * 16 * Nn + kn);
            a[i][1] = *(const float4*)(aptr + (size_t)i * 16 * Nn + kn + 4);
        }
        // 48 MFMA: 3-pass (hh + hl + lh), same order as previous rounds
#pragma unroll
        for (int i = 0; i < 4; ++i)
#pragma unroll
            for (int j = 0; j < 4; ++j) {
                acc[i][j] = __builtin_amdgcn_mfma_f32_16x16x32_bf16(ah[i], fbh[j], acc[i][j], 0, 0, 0);
                acc[i][j] = __builtin_amdgcn_mfma_f32_16x16x32_bf16(ah[i], fbl[j], acc[i][j], 0, 0, 0);
                acc[i][j] = __builtin_amdgcn_mfma_f32_16x16x32_bf16(al[i], fbh[j], acc[i][j], 0, 0, 0);
            }
    }

    // epilogue (identical mapping to previous rounds)
    const int row4 = (lane >> 4) * 4;
    const int col  = lane & 15;
    float* base = part + (size_t)s * PART_STRIDE;
#pragma unroll
    for (int i = 0; i < 4; ++i)
#pragma unroll
        for (int j = 0; j < 4; ++j) {
            const int n = bx * 128 + wn * 64 + j * 16 + col;
#pragma unroll
            for (int p = 0; p < 4; ++p) {
                const int m = m0 + wm * 64 + i * 16 + row4 + p;
                base[(size_t)m * HIDW + n] = acc[i][j][p];
            }
        }
}

// ---------------------------------------------------------------------------
// K2: one block per row — reduce KSPLIT partials, relu, dot w2 -> scores[row]
// (b2 omitted: constant shift doesn't change ordering)
// ---------------------------------------------------------------------------
__global__ __launch_bounds__(256) void score_rows(const float* __restrict__ part,
                                                  const float* __restrict__ b1,
                                                  const float* __restrict__ w2,
                                                  float* __restrict__ scores) {
    const int r = blockIdx.x;
    const int t = threadIdx.x;
    const size_t off = (size_t)r * HIDW + t;
    float h = 0.0f;
#pragma unroll
    for (int s = 0; s < KSPLIT; ++s) h += part[(size_t)s * PART_STRIDE + off];
    float p = fmaxf(h + b1[t], 0.0f) * w2[t];
#pragma unroll
    for (int o = 32; o > 0; o >>= 1) p += __shfl_down(p, o, 64);
    __shared__ float red[4];
    if ((t & 63) == 0) red[t >> 6] = p;
    __syncthreads();
    if (t == 0) scores[r] = red[0] + red[1] + red[2] + red[3];
}

// ---------------------------------------------------------------------------
// K3: gather + inline top-k — one block per (batch, sel).
// Each block redundantly computes the top-3 of its batch's 7 scores
// (deterministic float compares -> identical picks across blocks), copies its
// band, thread 0 writes the index output.
// ---------------------------------------------------------------------------
__global__ __launch_bounds__(256) void gather_bands(const float* __restrict__ x,
                                                    const float* __restrict__ scores,
                                                    float* __restrict__ out) {
    const int id = blockIdx.x;
    const int b  = id / SEL;
    const int kk = id - b * SEL;          // which of the top-3 this block copies
    float sc[Cc];
#pragma unroll
    for (int c = 0; c < Cc; ++c) sc[c] = scores[b * Cc + c];
    bool used[Cc] = {};
    int band = 0;
#pragma unroll
    for (int k = 0; k <= SEL - 1; ++k) {
        int best = 0;
        float bv = -3.4e38f;
#pragma unroll
        for (int c = 0; c < Cc; ++c)
            if (!used[c] && sc[c] > bv) { bv = sc[c]; best = c; }
        used[best] = true;
        if (k == kk) band = best;
        if (k > kk) break;
    }
    if (threadIdx.x == 0)
        out[(size_t)Bn * SEL * Nn + b * SEL + kk] = (float)band;
    const float4* src = (const float4*)(x + (size_t)(b * Cc + band) * Nn);
    float4* dst = (float4*)(out + (size_t)id * Nn);
    for (int i = threadIdx.x; i < Nn / 4; i += 256) dst[i] = src[i];
}

// ---------------------------------------------------------------------------
extern "C" void kernel_launch(void* const* d_in, const int* in_sizes, int n_in,
                              void* d_out, int out_size, void* d_ws, size_t ws_size,
                              hipStream_t stream) {
    const float* x  = (const float*)d_in[0];
    // d_in[1]=w_qkv, d_in[2]=b_qkv: dead in the reference forward
    const float* w1 = (const float*)d_in[3];
    const float* b1 = (const float*)d_in[4];
    const float* w2 = (const float*)d_in[5];
    const float* b2 = (const float*)d_in[6];
    (void)b2;
    float* out = (float*)d_out;

    char* ws = (char*)d_ws;
    float* part = (float*)ws;                                            // 29.36 MB
    unsigned short* bhi = (unsigned short*)(ws + KSPLIT * PART_STRIDE * sizeof(float));
    unsigned short* blo = bhi + (size_t)Nn * HIDW;                       // 8 MB each
    float* scores = (float*)(blo + (size_t)Nn * HIDW);

    convert_w1<<<(Nn / 32) * 16 * 64 / 256, 256, 0, stream>>>(w1, bhi, blo);
    gemm_mfma<<<14 * 2 * KSPLIT, 256, 0, stream>>>(x, bhi, blo, part);
    score_rows<<<Mrows, 256, 0, stream>>>(part, b1, w2, scores);
    gather_bands<<<Bn * SEL, 256, 0, stream>>>(x, scores, out);
}

// Round 9
// 264.902 us; speedup vs baseline: 1.1160x; 1.1160x over previous
//
#include <hip/hip_runtime.h>

#define Bn    256
#define Cc    7
#define Nn    16384
#define HIDW  256
#define SEL   3
#define Mrows (Bn * Cc)            // 1792
#define KSPLIT 16
#define KCHUNK (Nn / KSPLIT)       // 1024
#define BK    32
#define NIT   (KCHUNK / BK)        // 32
#define PART_STRIDE ((size_t)Mrows * HIDW)

typedef __attribute__((ext_vector_type(8))) short bf16x8;
typedef __attribute__((ext_vector_type(4))) float floatx4;

#if __has_builtin(__builtin_amdgcn_global_load_lds)
#define HAS_GLDS 1
#endif

#if __has_builtin(__builtin_amdgcn_sched_barrier)
#define SCHED_FENCE() __builtin_amdgcn_sched_barrier(0)
#else
#define SCHED_FENCE()
#endif

// pack high-16 bits of two fp32 words: low ushort = ua>>16, high = ub>>16
__device__ __forceinline__ unsigned pack_hi16(unsigned ua, unsigned ub) {
#if __has_builtin(__builtin_amdgcn_perm)
    return __builtin_amdgcn_perm(ub, ua, 0x07060302u);
#else
    return (ua >> 16) | (ub & 0xffff0000u);
#endif
}

// truncation hi/lo split of a pair of floats -> packed hi word + packed lo word
__device__ __forceinline__ void split2(float a, float b, unsigned& hp, unsigned& lp) {
    unsigned ua = __float_as_uint(a), ub = __float_as_uint(b);
    float fa = __uint_as_float(ua & 0xffff0000u);
    float fb = __uint_as_float(ub & 0xffff0000u);
    float la = a - fa, lb = b - fb;            // exact residuals
    hp = pack_hi16(ua, ub);
    lp = pack_hi16(__float_as_uint(la), __float_as_uint(lb));
}

// ---------------------------------------------------------------------------
// K0: w1[k][n] fp32 -> fragment-ordered bf16 hi/lo planes (trunc split).
// chunk(c,T,lane) holds B[k=c*32+(lane>>4)*8+j][n=T*16+(lane&15)], j=0..7,
// at ushort offset ((c*16+T)*64+lane)*8.   (unchanged from round-0)
// ---------------------------------------------------------------------------
__global__ __launch_bounds__(256) void convert_w1(const float* __restrict__ w1,
                                                  unsigned short* __restrict__ bhi,
                                                  unsigned short* __restrict__ blo) {
    const int id = blockIdx.x * 256 + threadIdx.x;
    const int l  = id & 63;
    const int ct = id >> 6;
    const int T  = ct & 15;
    const int c  = ct >> 4;
    const int n  = T * 16 + (l & 15);
    const int k  = c * 32 + (l >> 4) * 8;
    float f[8];
#pragma unroll
    for (int j = 0; j < 8; ++j) f[j] = w1[(size_t)(k + j) * HIDW + n];
    unsigned hp[4], lp[4];
#pragma unroll
    for (int m = 0; m < 4; ++m) split2(f[2 * m], f[2 * m + 1], hp[m], lp[m]);
    *(uint4*)(bhi + (size_t)id * 8) = make_uint4(hp[0], hp[1], hp[2], hp[3]);
    *(uint4*)(blo + (size_t)id * 8) = make_uint4(lp[0], lp[1], lp[2], lp[3]);
}

// ---------------------------------------------------------------------------
// K1: MFMA GEMM  part[s][M][256] = feat[M][Kslice] @ w1[Kslice][256]
//   128x128 tile, 4 waves 2x2, 16x16x32 bf16, 3-pass trunc hi/lo split.
//   ROUND-4 structure + ONE change: B LDS double-buffered with glds issued
//   one full iteration ahead (cross-barrier prefetch, T3/T4 "min 2-phase").
//   Issue order per iter: A(k+1) reg loads FIRST, then glds B(k+1); so
//   - split(k+1)'s compiler wait for A is vmcnt(4) (glds stay in flight)
//   - bar2(k)'s explicit vmcnt(8) retires exactly glds(k), issued an entire
//     iteration earlier -> its L2/L3 latency is hidden under 48 MFMAs+split.
//   Steady-state outstanding at iter entry: [A(k) x4, glds(k) x4].
//   Every iter issues exactly 4 A + 4 glds (dummies on the last iter).
// ---------------------------------------------------------------------------
__global__ __launch_bounds__(256) void gemm_mfma(const float* __restrict__ A,
                                                 const unsigned short* __restrict__ Bhi,
                                                 const unsigned short* __restrict__ Blo,
                                                 float* __restrict__ part) {
    __shared__ unsigned short Ah[4096], Al[4096];
    __shared__ unsigned short Bh[8192], Bl[8192];   // 2 buffers x 4096

    const int bx = blockIdx.x;
    const int m0 = blockIdx.y * 128;
    const int s  = blockIdx.z;
    const int k0 = s * KCHUNK;
    const int t  = threadIdx.x;
    const int lane = t & 63;
    const int w    = t >> 6;
    const int wm   = w & 1;
    const int wn   = w >> 1;

    const int ar  = t >> 1;
    const int kof = (t & 1) * 16;
    const float* aptr = A + (size_t)(m0 + ar) * Nn + k0 + kof;
    const int aidx0 = (ar >> 4) * 512 + ((ar & 15) + ((kof >> 3) + 0) * 16) * 8;
    const int aidx1 = (ar >> 4) * 512 + ((ar & 15) + ((kof >> 3) + 1) * 16) * 8;
    const int wbase = (t & 192) * 8;   // wave-uniform LDS ushort base for glds

    floatx4 acc[4][4];
#pragma unroll
    for (int i = 0; i < 4; ++i)
#pragma unroll
        for (int j = 0; j < 4; ++j) acc[i][j] = (floatx4)0.0f;

    // ---- prologue: A(0) regs first (older), then glds B(0) -> buf0 (newer)
    float4 pa0 = *(const float4*)(aptr + 0);
    float4 pa1 = *(const float4*)(aptr + 4);
    float4 pa2 = *(const float4*)(aptr + 8);
    float4 pa3 = *(const float4*)(aptr + 12);
    SCHED_FENCE();
    {
        const size_t bbase = ((size_t)((k0 >> 5) * 16 + bx * 8)) * 512;
#ifdef HAS_GLDS
        __builtin_amdgcn_global_load_lds(
            (const __attribute__((address_space(1))) void*)(Bhi + bbase + t * 8),
            (__attribute__((address_space(3))) void*)&Bh[wbase], 16, 0, 0);
        __builtin_amdgcn_global_load_lds(
            (const __attribute__((address_space(1))) void*)(Bhi + bbase + 2048 + t * 8),
            (__attribute__((address_space(3))) void*)&Bh[2048 + wbase], 16, 0, 0);
        __builtin_amdgcn_global_load_lds(
            (const __attribute__((address_space(1))) void*)(Blo + bbase + t * 8),
            (__attribute__((address_space(3))) void*)&Bl[wbase], 16, 0, 0);
        __builtin_amdgcn_global_load_lds(
            (const __attribute__((address_space(1))) void*)(Blo + bbase + 2048 + t * 8),
            (__attribute__((address_space(3))) void*)&Bl[2048 + wbase], 16, 0, 0);
#else
        *(uint4*)&Bh[t * 8]        = *(const uint4*)(Bhi + bbase + t * 8);
        *(uint4*)&Bh[2048 + t * 8] = *(const uint4*)(Bhi + bbase + 2048 + t * 8);
        *(uint4*)&Bl[t * 8]        = *(const uint4*)(Blo + bbase + t * 8);
        *(uint4*)&Bl[2048 + t * 8] = *(const uint4*)(Blo + bbase + 2048 + t * 8);
#endif
    }
    SCHED_FENCE();

    for (int it = 0; it < NIT; ++it) {
        const int kk = it * BK;
        const int pb = it & 1;          // B buffer read this iteration
        // ---- split A(k) (compiler waits vmcnt(4): A older than glds(k))
        float af[16] = {pa0.x, pa0.y, pa0.z, pa0.w, pa1.x, pa1.y, pa1.z, pa1.w,
                        pa2.x, pa2.y, pa2.z, pa2.w, pa3.x, pa3.y, pa3.z, pa3.w};
        unsigned hp[8], lp[8];
#pragma unroll
        for (int m = 0; m < 8; ++m) split2(af[2 * m], af[2 * m + 1], hp[m], lp[m]);

        // ---- barrier #1: raw (prev frag reads retired; keep glds(k) in flight)
        SCHED_FENCE();
        __builtin_amdgcn_s_barrier();
        SCHED_FENCE();

        // ---- issue A(k+1) (older) then glds B(k+1) -> buf pb^1 (newer)
        const int kn = (kk + BK < KCHUNK) ? (kk + BK) : kk;   // clamped dummy
        pa0 = *(const float4*)(aptr + kn + 0);
        pa1 = *(const float4*)(aptr + kn + 4);
        pa2 = *(const float4*)(aptr + kn + 8);
        pa3 = *(const float4*)(aptr + kn + 12);
        SCHED_FENCE();
        {
            const size_t bbase = ((size_t)(((k0 + kn) >> 5) * 16 + bx * 8)) * 512;
            const int db = (pb ^ 1) * 4096 + wbase;
#ifdef HAS_GLDS
            __builtin_amdgcn_global_load_lds(
                (const __attribute__((address_space(1))) void*)(Bhi + bbase + t * 8),
                (__attribute__((address_space(3))) void*)&Bh[db], 16, 0, 0);
            __builtin_amdgcn_global_load_lds(
                (const __attribute__((address_space(1))) void*)(Bhi + bbase + 2048 + t * 8),
                (__attribute__((address_space(3))) void*)&Bh[db + 2048], 16, 0, 0);
            __builtin_amdgcn_global_load_lds(
                (const __attribute__((address_space(1))) void*)(Blo + bbase + t * 8),
                (__attribute__((address_space(3))) void*)&Bl[db], 16, 0, 0);
            __builtin_amdgcn_global_load_lds(
                (const __attribute__((address_space(1))) void*)(Blo + bbase + 2048 + t * 8),
                (__attribute__((address_space(3))) void*)&Bl[db + 2048], 16, 0, 0);
#else
            const int ds = (pb ^ 1) * 4096;
            *(uint4*)&Bh[ds + t * 8]        = *(const uint4*)(Bhi + bbase + t * 8);
            *(uint4*)&Bh[ds + 2048 + t * 8] = *(const uint4*)(Bhi + bbase + 2048 + t * 8);
            *(uint4*)&Bl[ds + t * 8]        = *(const uint4*)(Blo + bbase + t * 8);
            *(uint4*)&Bl[ds + 2048 + t * 8] = *(const uint4*)(Blo + bbase + 2048 + t * 8);
#endif
        }
        // ---- A ds_writes (current k, single A buffer)
        *(uint4*)&Ah[aidx0] = make_uint4(hp[0], hp[1], hp[2], hp[3]);
        *(uint4*)&Ah[aidx1] = make_uint4(hp[4], hp[5], hp[6], hp[7]);
        *(uint4*)&Al[aidx0] = make_uint4(lp[0], lp[1], lp[2], lp[3]);
        *(uint4*)&Al[aidx1] = make_uint4(lp[4], lp[5], lp[6], lp[7]);

        // ---- barrier #2: retire glds(k) (oldest 4 of 12) + ds_writes;
        //      A(k+1) and glds(k+1) stay in flight across the MFMA phase.
        SCHED_FENCE();
#ifdef HAS_GLDS
        asm volatile("s_waitcnt vmcnt(8) lgkmcnt(0)" ::: "memory");
#else
        asm volatile("s_waitcnt vmcnt(8) lgkmcnt(0)" ::: "memory");
#endif
        __builtin_amdgcn_s_barrier();
        SCHED_FENCE();

        // ---- fragment reads (buf pb) + 48 MFMA
        bf16x8 fah[4], fal[4], fbh[4], fbl[4];
#pragma unroll
        for (int i = 0; i < 4; ++i) {
            fah[i] = *(const bf16x8*)&Ah[(wm * 4 + i) * 512 + lane * 8];
            fal[i] = *(const bf16x8*)&Al[(wm * 4 + i) * 512 + lane * 8];
        }
#pragma unroll
        for (int j = 0; j < 4; ++j) {
            fbh[j] = *(const bf16x8*)&Bh[pb * 4096 + (wn * 4 + j) * 512 + lane * 8];
            fbl[j] = *(const bf16x8*)&Bl[pb * 4096 + (wn * 4 + j) * 512 + lane * 8];
        }
#pragma unroll
        for (int i = 0; i < 4; ++i)
#pragma unroll
            for (int j = 0; j < 4; ++j) {
                acc[i][j] = __builtin_amdgcn_mfma_f32_16x16x32_bf16(fah[i], fbh[j], acc[i][j], 0, 0, 0);
                acc[i][j] = __builtin_amdgcn_mfma_f32_16x16x32_bf16(fah[i], fbl[j], acc[i][j], 0, 0, 0);
                acc[i][j] = __builtin_amdgcn_mfma_f32_16x16x32_bf16(fal[i], fbh[j], acc[i][j], 0, 0, 0);
            }
    }

    const int row4 = (lane >> 4) * 4;
    const int col  = lane & 15;
    float* base = part + (size_t)s * PART_STRIDE;
#pragma unroll
    for (int i = 0; i < 4; ++i)
#pragma unroll
        for (int j = 0; j < 4; ++j) {
            const int n = bx * 128 + wn * 64 + j * 16 + col;
#pragma unroll
            for (int p = 0; p < 4; ++p) {
                const int m = m0 + wm * 64 + i * 16 + row4 + p;
                base[(size_t)m * HIDW + n] = acc[i][j][p];
            }
        }
}

// ---------------------------------------------------------------------------
// K2: one block per row — reduce KSPLIT partials, relu, dot w2 -> scores[row]
// (b2 omitted: constant shift doesn't change ordering)
// ---------------------------------------------------------------------------
__global__ __launch_bounds__(256) void score_rows(const float* __restrict__ part,
                                                  const float* __restrict__ b1,
                                                  const float* __restrict__ w2,
                                                  float* __restrict__ scores) {
    const int r = blockIdx.x;
    const int t = threadIdx.x;
    const size_t off = (size_t)r * HIDW + t;
    float h = 0.0f;
#pragma unroll
    for (int s = 0; s < KSPLIT; ++s) h += part[(size_t)s * PART_STRIDE + off];
    float p = fmaxf(h + b1[t], 0.0f) * w2[t];
#pragma unroll
    for (int o = 32; o > 0; o >>= 1) p += __shfl_down(p, o, 64);
    __shared__ float red[4];
    if ((t & 63) == 0) red[t >> 6] = p;
    __syncthreads();
    if (t == 0) scores[r] = red[0] + red[1] + red[2] + red[3];
}

// ---------------------------------------------------------------------------
// K3: gather + inline top-k — one block per (batch, sel).
// Each block redundantly computes the top-3 of its batch's 7 scores
// (deterministic float compares -> identical picks across blocks), copies its
// band, thread 0 writes the index output.
// ---------------------------------------------------------------------------
__global__ __launch_bounds__(256) void gather_bands(const float* __restrict__ x,
                                                    const float* __restrict__ scores,
                                                    float* __restrict__ out) {
    const int id = blockIdx.x;
    const int b  = id / SEL;
    const int kk = id - b * SEL;          // which of the top-3 this block copies
    float sc[Cc];
#pragma unroll
    for (int c = 0; c < Cc; ++c) sc[c] = scores[b * Cc + c];
    bool used[Cc] = {};
    int band = 0;
#pragma unroll
    for (int k = 0; k <= SEL - 1; ++k) {
        int best = 0;
        float bv = -3.4e38f;
#pragma unroll
        for (int c = 0; c < Cc; ++c)
            if (!used[c] && sc[c] > bv) { bv = sc[c]; best = c; }
        used[best] = true;
        if (k == kk) band = best;
        if (k > kk) break;
    }
    if (threadIdx.x == 0)
        out[(size_t)Bn * SEL * Nn + b * SEL + kk] = (float)band;
    const float4* src = (const float4*)(x + (size_t)(b * Cc + band) * Nn);
    float4* dst = (float4*)(out + (size_t)id * Nn);
    for (int i = threadIdx.x; i < Nn / 4; i += 256) dst[i] = src[i];
}

// ---------------------------------------------------------------------------
extern "C" void kernel_launch(void* const* d_in, const int* in_sizes, int n_in,
                              void* d_out, int out_size, void* d_ws, size_t ws_size,
                              hipStream_t stream) {
    const float* x  = (const float*)d_in[0];
    // d_in[1]=w_qkv, d_in[2]=b_qkv: dead in the reference forward
    const float* w1 = (const float*)d_in[3];
    const float* b1 = (const float*)d_in[4];
    const float* w2 = (const float*)d_in[5];
    const float* b2 = (const float*)d_in[6];
    (void)b2;
    float* out = (float*)d_out;

    char* ws = (char*)d_ws;
    float* part = (float*)ws;                                            // 29.36 MB
    unsigned short* bhi = (unsigned short*)(ws + KSPLIT * PART_STRIDE * sizeof(float));
    unsigned short* blo = bhi + (size_t)Nn * HIDW;                       // 8 MB each
    float* scores = (float*)(blo + (size_t)Nn * HIDW);

    convert_w1<<<(Nn / 32) * 16 * 64 / 256, 256, 0, stream>>>(w1, bhi, blo);
    gemm_mfma<<<dim3(HIDW / 128, Mrows / 128, KSPLIT), 256, 0, stream>>>(x, bhi, blo, part);
    score_rows<<<Mrows, 256, 0, stream>>>(part, b1, w2, scores);
    gather_bands<<<Bn * SEL, 256, 0, stream>>>(x, scores, out);
}